// Round 1
// baseline (1704.327 us; speedup 1.0000x reference)
//
#include <hip/hip_runtime.h>
#include <hip/hip_fp16.h>

#define G      160
#define G3     (G*G*G)
#define NRAYS  4096
#define SAMP   256
#define CK0    12
#define HID    128

// log(1/(1-0.01) - 1) = -log(99)
#define ACT_SHIFT (-4.59511985013459f)

// ---------- helpers ----------
__device__ __forceinline__ unsigned short f2bf(float x) {
    unsigned u = __float_as_uint(x);
    unsigned r = u + 0x7fffu + ((u >> 16) & 1u);   // RNE
    return (unsigned short)(r >> 16);
}
__device__ __forceinline__ float bflo(unsigned u) { return __uint_as_float(u << 16); }
__device__ __forceinline__ float bfhi(unsigned u) { return __uint_as_float(u & 0xffff0000u); }

// ---------- prepass: interleave density + k0 into [x][y][z][16] bf16 ----------
__global__ __launch_bounds__(256) void prepass_kernel(
        const float* __restrict__ dgrid,   // [1,G,G,G]
        const float* __restrict__ kgrid,   // [12,G,G,G]
        unsigned short* __restrict__ vox)  // [G3][16] bf16
{
    int v = blockIdx.x * blockDim.x + threadIdx.x;
    if (v >= G3) return;
    union { unsigned short h[16]; uint4 q[2]; } u;
    u.h[0] = f2bf(dgrid[v]);
#pragma unroll
    for (int c = 0; c < CK0; c++) u.h[c + 1] = f2bf(kgrid[(size_t)c * G3 + v]);
    u.h[13] = 0; u.h[14] = 0; u.h[15] = 0;
    uint4* dst = reinterpret_cast<uint4*>(vox) + (size_t)v * 2;
    dst[0] = u.q[0];
    dst[1] = u.q[1];
}

// ---------- main: one block per ray, one thread per sample ----------
template <bool VOX>
__global__ __launch_bounds__(256, 2) void dvgo_main(
        const float* __restrict__ pts,       // [N,S,3]
        const float* __restrict__ viewdirs,  // [N,3]
        const float* __restrict__ dgrid,     // fallback
        const float* __restrict__ kgrid,     // fallback
        const unsigned short* __restrict__ vox,
        const float* __restrict__ w0, const float* __restrict__ b0,
        const float* __restrict__ w1, const float* __restrict__ b1,
        const float* __restrict__ w2, const float* __restrict__ b2,
        float* __restrict__ out)             // [N,3]
{
    const int n = blockIdx.x;
    const int t = threadIdx.x;

    __shared__ float  s_alpha[SAMP];
    __shared__ float  s_P[SAMP];
    __shared__ __half s_h1[SAMP * 132];      // per-thread private row, stride 132
    __shared__ float  s_red[12];

    // ---- load point, trilinear setup ----
    const float* p = pts + ((size_t)n * SAMP + t) * 3;
    float px = p[0], py = p[1], pz = p[2];

    int   i0[3];
    float fr[3];
    float pc[3] = {px, py, pz};
#pragma unroll
    for (int d = 0; d < 3; d++) {
        float uu = (pc[d] + 1.0f) * 0.5f * (float)(G - 1);
        uu = fminf(fmaxf(uu, 0.0f), (float)(G - 1));
        int i = (int)floorf(uu);
        if (i > G - 2) i = G - 2;
        i0[d] = i;
        fr[d] = uu - (float)i;
    }

    float dens = 0.0f;
    float k0v[CK0];
#pragma unroll
    for (int c = 0; c < CK0; c++) k0v[c] = 0.0f;

#pragma unroll
    for (int cx = 0; cx < 2; cx++) {
        float wx = cx ? fr[0] : 1.0f - fr[0];
#pragma unroll
        for (int cy = 0; cy < 2; cy++) {
            float wxy = wx * (cy ? fr[1] : 1.0f - fr[1]);
#pragma unroll
            for (int cz = 0; cz < 2; cz++) {
                float w = wxy * (cz ? fr[2] : 1.0f - fr[2]);
                int vidx = ((i0[0] + cx) * G + (i0[1] + cy)) * G + (i0[2] + cz);
                if (VOX) {
                    const uint4* q = reinterpret_cast<const uint4*>(vox) + (size_t)vidx * 2;
                    uint4 A = q[0];
                    uint4 B = q[1];
                    dens    += w * bflo(A.x);
                    k0v[0]  += w * bfhi(A.x);
                    k0v[1]  += w * bflo(A.y);
                    k0v[2]  += w * bfhi(A.y);
                    k0v[3]  += w * bflo(A.z);
                    k0v[4]  += w * bfhi(A.z);
                    k0v[5]  += w * bflo(A.w);
                    k0v[6]  += w * bfhi(A.w);
                    k0v[7]  += w * bflo(B.x);
                    k0v[8]  += w * bfhi(B.x);
                    k0v[9]  += w * bflo(B.y);
                    k0v[10] += w * bfhi(B.y);
                    k0v[11] += w * bflo(B.z);
                } else {
                    dens += w * dgrid[vidx];
#pragma unroll
                    for (int c = 0; c < CK0; c++)
                        k0v[c] += w * kgrid[(size_t)c * G3 + vidx];
                }
            }
        }
    }

    // ---- alpha ----
    float xs = dens + ACT_SHIFT;
    float sp = (xs > 20.0f) ? xs : log1pf(expf(xs));
    float alpha = 1.0f - expf(-sp * 0.5f);

    // ---- inclusive cumprod scan of (1-alpha) over the ray ----
    s_alpha[t] = alpha;
    s_P[t] = 1.0f - alpha;
    __syncthreads();
#pragma unroll
    for (int off = 1; off < SAMP; off <<= 1) {
        float v = (t >= off) ? s_P[t - off] : 1.0f;
        __syncthreads();
        s_P[t] *= v;
        __syncthreads();
    }

    // ---- view embedding (recomputed per thread; cheap) ----
    float v0 = viewdirs[n * 3 + 0];
    float v1 = viewdirs[n * 3 + 1];
    float v2 = viewdirs[n * 3 + 2];
    float inv = 1.0f / sqrtf(v0 * v0 + v1 * v1 + v2 * v2);
    v0 *= inv; v1 *= inv; v2 *= inv;

    float feat[39];
#pragma unroll
    for (int c = 0; c < CK0; c++) feat[c] = k0v[c];
    feat[12] = v0; feat[13] = v1; feat[14] = v2;
    {
        float vd3[3] = {v0, v1, v2};
#pragma unroll
        for (int i = 0; i < 3; i++) {
#pragma unroll
            for (int j = 0; j < 4; j++) {
                float a = vd3[i] * (float)(1 << j);
                feat[15 + i * 4 + j] = sinf(a);
                feat[27 + i * 4 + j] = cosf(a);
            }
        }
    }

    // ---- layer 1: feat[39] @ w0[39,128] + b0 -> relu -> s_h1 (fp16) ----
    const int hrow = t * 132;
#pragma unroll 1
    for (int ch = 0; ch < 4; ch++) {
        float acc[32];
#pragma unroll
        for (int j = 0; j < 32; j++) acc[j] = b0[ch * 32 + j];
#pragma unroll
        for (int k = 0; k < 39; k++) {
            float f = feat[k];
#pragma unroll
            for (int j = 0; j < 32; j++)
                acc[j] = fmaf(f, w0[k * HID + ch * 32 + j], acc[j]);
        }
#pragma unroll
        for (int j = 0; j < 32; j++)
            s_h1[hrow + ch * 32 + j] = __float2half(fmaxf(acc[j], 0.0f));
    }
    // each thread reads only its own row -> no syncthreads needed

    // ---- layer 2 (128->128, relu) fused with layer 3 (128->3) ----
    float rgbpre[3] = {b2[0], b2[1], b2[2]};
#pragma unroll 1
    for (int ch = 0; ch < 4; ch++) {
        float acc[32];
#pragma unroll
        for (int j = 0; j < 32; j++) acc[j] = b1[ch * 32 + j];
#pragma unroll 4
        for (int k = 0; k < HID; k++) {
            float hk = __half2float(s_h1[hrow + k]);
#pragma unroll
            for (int j = 0; j < 32; j++)
                acc[j] = fmaf(hk, w1[k * HID + ch * 32 + j], acc[j]);
        }
#pragma unroll
        for (int j = 0; j < 32; j++) {
            float h2 = fmaxf(acc[j], 0.0f);
            int jj = ch * 32 + j;
            rgbpre[0] = fmaf(h2, w2[jj * 3 + 0], rgbpre[0]);
            rgbpre[1] = fmaf(h2, w2[jj * 3 + 1], rgbpre[1]);
            rgbpre[2] = fmaf(h2, w2[jj * 3 + 2], rgbpre[2]);
        }
    }

    float rgb0 = 1.0f / (1.0f + expf(-rgbpre[0]));
    float rgb1 = 1.0f / (1.0f + expf(-rgbpre[1]));
    float rgb2 = 1.0f / (1.0f + expf(-rgbpre[2]));

    // ---- weighted march + reduction ----
    float T_excl = (t == 0) ? 1.0f : s_P[t - 1];
    float wgt = s_alpha[t] * T_excl;
    float c0 = wgt * rgb0, c1 = wgt * rgb1, c2 = wgt * rgb2;

#pragma unroll
    for (int off = 32; off > 0; off >>= 1) {
        c0 += __shfl_down(c0, off);
        c1 += __shfl_down(c1, off);
        c2 += __shfl_down(c2, off);
    }
    if ((t & 63) == 0) {
        int wv = t >> 6;
        s_red[wv * 3 + 0] = c0;
        s_red[wv * 3 + 1] = c1;
        s_red[wv * 3 + 2] = c2;
    }
    __syncthreads();
    if (t == 0) {
        float alast = s_P[SAMP - 1];
        float o0 = alast, o1 = alast, o2 = alast;
#pragma unroll
        for (int wv = 0; wv < 4; wv++) {
            o0 += s_red[wv * 3 + 0];
            o1 += s_red[wv * 3 + 1];
            o2 += s_red[wv * 3 + 2];
        }
        out[n * 3 + 0] = o0;
        out[n * 3 + 1] = o1;
        out[n * 3 + 2] = o2;
    }
}

extern "C" void kernel_launch(void* const* d_in, const int* in_sizes, int n_in,
                              void* d_out, int out_size, void* d_ws, size_t ws_size,
                              hipStream_t stream) {
    const float* pts      = (const float*)d_in[0];
    const float* viewdirs = (const float*)d_in[1];
    const float* dgrid    = (const float*)d_in[2];
    const float* kgrid    = (const float*)d_in[3];
    const float* w0       = (const float*)d_in[4];
    const float* b0       = (const float*)d_in[5];
    const float* w1       = (const float*)d_in[6];
    const float* b1       = (const float*)d_in[7];
    const float* w2       = (const float*)d_in[8];
    const float* b2       = (const float*)d_in[9];
    float* out = (float*)d_out;

    const size_t vox_bytes = (size_t)G3 * 16 * sizeof(unsigned short);

    if (ws_size >= vox_bytes) {
        unsigned short* vox = (unsigned short*)d_ws;
        prepass_kernel<<<(G3 + 255) / 256, 256, 0, stream>>>(dgrid, kgrid, vox);
        dvgo_main<true><<<NRAYS, SAMP, 0, stream>>>(
            pts, viewdirs, dgrid, kgrid, vox,
            w0, b0, w1, b1, w2, b2, out);
    } else {
        dvgo_main<false><<<NRAYS, SAMP, 0, stream>>>(
            pts, viewdirs, dgrid, kgrid, nullptr,
            w0, b0, w1, b1, w2, b2, out);
    }
}

// Round 2
// 551.502 us; speedup vs baseline: 3.0903x; 3.0903x over previous
//
#include <hip/hip_runtime.h>

#define G      160
#define G3     (G*G*G)
#define NRAYS  4096
#define SAMP   256
#define CK0    12
#define HID    128

// log(1/(1-0.01) - 1) = -log(99)
#define ACT_SHIFT (-4.59511985013459f)

#define FS 72    // feat LDS row stride (halves): 64 data + 8 pad -> 2-way-only conflicts
#define HS 136   // h1/h2 LDS row stride (halves): 128 data + 8 pad

typedef __attribute__((ext_vector_type(8))) short bf16x8;
typedef __attribute__((ext_vector_type(4))) float f32x4;

// ---------- helpers ----------
__device__ __forceinline__ unsigned short f2bf(float x) {
    unsigned u = __float_as_uint(x);
    unsigned r = u + 0x7fffu + ((u >> 16) & 1u);   // RNE
    return (unsigned short)(r >> 16);
}
__device__ __forceinline__ float bflo(unsigned u) { return __uint_as_float(u << 16); }
__device__ __forceinline__ float bfhi(unsigned u) { return __uint_as_float(u & 0xffff0000u); }
__device__ __forceinline__ unsigned pack2(float a, float b) {
    return (unsigned)f2bf(a) | ((unsigned)f2bf(b) << 16);
}

// ---------- prepass: interleave density + k0 into [x][y][z][16] bf16, 4 voxels/thread ----------
__global__ __launch_bounds__(256) void prepass_kernel(
        const float* __restrict__ dgrid,   // [1,G,G,G]
        const float* __restrict__ kgrid,   // [12,G,G,G]
        unsigned short* __restrict__ vox)  // [G3][16] bf16
{
    int v4 = (blockIdx.x * 256 + threadIdx.x) * 4;
    if (v4 >= G3) return;
    union F4 { float4 v; float f[4]; };
    F4 d; d.v = *reinterpret_cast<const float4*>(dgrid + v4);
    F4 kk[CK0];
#pragma unroll
    for (int c = 0; c < CK0; c++)
        kk[c].v = *reinterpret_cast<const float4*>(kgrid + (size_t)c * G3 + v4);
#pragma unroll
    for (int i = 0; i < 4; i++) {
        uint4 qa, qb;
        qa.x = pack2(d.f[i],      kk[0].f[i]);
        qa.y = pack2(kk[1].f[i],  kk[2].f[i]);
        qa.z = pack2(kk[3].f[i],  kk[4].f[i]);
        qa.w = pack2(kk[5].f[i],  kk[6].f[i]);
        qb.x = pack2(kk[7].f[i],  kk[8].f[i]);
        qb.y = pack2(kk[9].f[i],  kk[10].f[i]);
        qb.z = pack2(kk[11].f[i], 0.0f);
        qb.w = 0u;
        uint4* dst = reinterpret_cast<uint4*>(vox + (size_t)(v4 + i) * 16);
        dst[0] = qa;
        dst[1] = qb;
    }
}

// ---------- weight prepack into B-fragment order for mfma_f32_16x16x32_bf16 ----------
// frag f covers (nt = f/KS, ks = f%KS); lane l, j: element W[k][n],
// k = ks*32 + (l>>4)*8 + j, n = nt*16 + (l&15); stored at [(f*64+l)*8+j].
__global__ void pack_weights(const float* __restrict__ w0,
                             const float* __restrict__ w1,
                             const float* __restrict__ w2,
                             unsigned short* __restrict__ w0p,
                             unsigned short* __restrict__ w1p,
                             unsigned short* __restrict__ w2p)
{
    int t = threadIdx.x;
    // w0: K 39->64 (KS=2), N=128 (NT=8) -> 16 frags
    for (int idx = t; idx < 16 * 512; idx += 256) {
        int f = idx >> 9, r = idx & 511, l = r >> 3, j = r & 7;
        int nt = f >> 1, ks = f & 1;
        int k = ks * 32 + ((l >> 4) << 3) + j;
        int n = nt * 16 + (l & 15);
        w0p[idx] = (k < 39) ? f2bf(w0[k * HID + n]) : (unsigned short)0;
    }
    // w1: K=128 (KS=4), N=128 (NT=8) -> 32 frags
    for (int idx = t; idx < 32 * 512; idx += 256) {
        int f = idx >> 9, r = idx & 511, l = r >> 3, j = r & 7;
        int nt = f >> 2, ks = f & 3;
        int k = ks * 32 + ((l >> 4) << 3) + j;
        int n = nt * 16 + (l & 15);
        w1p[idx] = f2bf(w1[k * HID + n]);
    }
    // w2: K=128 (KS=4), N 3->16 (NT=1) -> 4 frags
    for (int idx = t; idx < 4 * 512; idx += 256) {
        int f = idx >> 9, r = idx & 511, l = r >> 3, j = r & 7;
        int ks = f;
        int k = ks * 32 + ((l >> 4) << 3) + j;
        int n = (l & 15);
        w2p[idx] = (n < 3) ? f2bf(w2[k * 3 + n]) : (unsigned short)0;
    }
}

// ---------- main: one block per ray; 4 waves; wave = 64-row M-tile MFMA MLP ----------
__global__ __launch_bounds__(256) void dvgo_mfma(
        const float* __restrict__ pts,       // [N,S,3]
        const float* __restrict__ viewdirs,  // [N,3]
        const unsigned short* __restrict__ vox,
        const unsigned short* __restrict__ w0p,
        const unsigned short* __restrict__ w1p,
        const unsigned short* __restrict__ w2p,
        const float* __restrict__ b0, const float* __restrict__ b1,
        const float* __restrict__ b2,
        float* __restrict__ out)             // [N,3]
{
    __shared__ unsigned short s_mem[SAMP * HS];   // feat (stride FS) then h1/h2 (stride HS)
    __shared__ float s_alpha[SAMP];
    __shared__ float s_P[SAMP];
    __shared__ float s_out[4];

    const int n = blockIdx.x;
    const int t = threadIdx.x;
    const int lane = t & 63;
    const int wv = t >> 6;
    const int wbase = wv << 6;
    const int c    = lane & 15;   // C/D col index, B n index, A m index
    const int quad = lane >> 4;

    if (t < 4) s_out[t] = 0.0f;

    // ---- gather ----
    const float* p = pts + ((size_t)n * SAMP + t) * 3;
    float pc[3] = {p[0], p[1], p[2]};
    int   i0[3];
    float fr[3];
#pragma unroll
    for (int d = 0; d < 3; d++) {
        float uu = (pc[d] + 1.0f) * 0.5f * (float)(G - 1);
        uu = fminf(fmaxf(uu, 0.0f), (float)(G - 1));
        int i = (int)floorf(uu);
        if (i > G - 2) i = G - 2;
        i0[d] = i;
        fr[d] = uu - (float)i;
    }

    float dens = 0.0f;
    float k0v[CK0];
#pragma unroll
    for (int ch = 0; ch < CK0; ch++) k0v[ch] = 0.0f;

#pragma unroll
    for (int cx = 0; cx < 2; cx++) {
        float wx = cx ? fr[0] : 1.0f - fr[0];
#pragma unroll
        for (int cy = 0; cy < 2; cy++) {
            float wxy = wx * (cy ? fr[1] : 1.0f - fr[1]);
#pragma unroll
            for (int cz = 0; cz < 2; cz++) {
                float wgt = wxy * (cz ? fr[2] : 1.0f - fr[2]);
                int vidx = ((i0[0] + cx) * G + (i0[1] + cy)) * G + (i0[2] + cz);
                const uint4* q = reinterpret_cast<const uint4*>(vox) + (size_t)vidx * 2;
                uint4 A = q[0];
                uint4 B = q[1];
                dens    += wgt * bflo(A.x);
                k0v[0]  += wgt * bfhi(A.x);
                k0v[1]  += wgt * bflo(A.y);
                k0v[2]  += wgt * bfhi(A.y);
                k0v[3]  += wgt * bflo(A.z);
                k0v[4]  += wgt * bfhi(A.z);
                k0v[5]  += wgt * bflo(A.w);
                k0v[6]  += wgt * bfhi(A.w);
                k0v[7]  += wgt * bflo(B.x);
                k0v[8]  += wgt * bfhi(B.x);
                k0v[9]  += wgt * bflo(B.y);
                k0v[10] += wgt * bfhi(B.y);
                k0v[11] += wgt * bflo(B.z);
            }
        }
    }

    // ---- alpha ----
    float xs = dens + ACT_SHIFT;
    float sp = (xs > 20.0f) ? xs : log1pf(expf(xs));
    float alpha = 1.0f - expf(-sp * 0.5f);
    s_alpha[t] = alpha;
    s_P[t] = 1.0f - alpha;

    // ---- view embedding + feature vector (39 used, zero-pad to 64) ----
    float v0 = viewdirs[n * 3 + 0];
    float v1 = viewdirs[n * 3 + 1];
    float v2 = viewdirs[n * 3 + 2];
    float inv = 1.0f / sqrtf(v0 * v0 + v1 * v1 + v2 * v2);
    v0 *= inv; v1 *= inv; v2 *= inv;

    float feat[40];
#pragma unroll
    for (int ch = 0; ch < CK0; ch++) feat[ch] = k0v[ch];
    feat[12] = v0; feat[13] = v1; feat[14] = v2;
    {
        float vd3[3] = {v0, v1, v2};
#pragma unroll
        for (int i = 0; i < 3; i++) {
#pragma unroll
            for (int j = 0; j < 4; j++) {
                float a = vd3[i] * (float)(1 << j);
                feat[15 + i * 4 + j] = sinf(a);
                feat[27 + i * 4 + j] = cosf(a);
            }
        }
    }
    feat[39] = 0.0f;

    // write feat row (bf16) to LDS, 16B chunks; rows 39..63 zero
#pragma unroll
    for (int ch = 0; ch < 8; ch++) {
        uint4 q;
        if (ch < 5) {
            q.x = pack2(feat[ch * 8 + 0], feat[ch * 8 + 1]);
            q.y = pack2(feat[ch * 8 + 2], feat[ch * 8 + 3]);
            q.z = pack2(feat[ch * 8 + 4], feat[ch * 8 + 5]);
            q.w = pack2(feat[ch * 8 + 6], feat[ch * 8 + 7]);
        } else {
            q.x = 0u; q.y = 0u; q.z = 0u; q.w = 0u;
        }
        *reinterpret_cast<uint4*>(&s_mem[t * FS + ch * 8]) = q;
    }

    // ---- inclusive cumprod scan of (1-alpha) ----
    __syncthreads();
#pragma unroll
    for (int off = 1; off < SAMP; off <<= 1) {
        float v = (t >= off) ? s_P[t - off] : 1.0f;
        __syncthreads();
        s_P[t] *= v;
        __syncthreads();
    }

    const f32x4 zf = {0.0f, 0.0f, 0.0f, 0.0f};

    // ---- load A1 fragments (feat), then free feat region ----
    bf16x8 a1[4][2];
#pragma unroll
    for (int mt = 0; mt < 4; mt++)
#pragma unroll
        for (int ks = 0; ks < 2; ks++)
            a1[mt][ks] = *reinterpret_cast<const bf16x8*>(
                &s_mem[(wbase + mt * 16 + c) * FS + ks * 32 + quad * 8]);
    __syncthreads();   // all waves done reading feat; safe to overwrite with h1

    // ---- layer 1: [256,64]@[64,128] + b0, relu -> h1 in LDS ----
    const uint4* w0q = reinterpret_cast<const uint4*>(w0p);
#pragma unroll
    for (int nt = 0; nt < 8; nt++) {
        union { uint4 q; bf16x8 s; } bA, bB;
        bA.q = w0q[(nt * 2 + 0) * 64 + lane];
        bB.q = w0q[(nt * 2 + 1) * 64 + lane];
        f32x4 acc[4];
#pragma unroll
        for (int mt = 0; mt < 4; mt++) {
            f32x4 tmp = __builtin_amdgcn_mfma_f32_16x16x32_bf16(a1[mt][0], bA.s, zf, 0, 0, 0);
            acc[mt]   = __builtin_amdgcn_mfma_f32_16x16x32_bf16(a1[mt][1], bB.s, tmp, 0, 0, 0);
        }
        float bias = b0[nt * 16 + c];
#pragma unroll
        for (int mt = 0; mt < 4; mt++)
#pragma unroll
            for (int r = 0; r < 4; r++) {
                float h = fmaxf(acc[mt][r] + bias, 0.0f);
                s_mem[(wbase + mt * 16 + quad * 4 + r) * HS + nt * 16 + c] = f2bf(h);
            }
    }
    // wave reads/writes only its own 64 rows from here on -> no barrier needed

    // ---- layer 2: h1@w1 + b1, relu -> h2 in LDS (same region/rows) ----
    bf16x8 a2[4][4];
#pragma unroll
    for (int mt = 0; mt < 4; mt++)
#pragma unroll
        for (int ks = 0; ks < 4; ks++)
            a2[mt][ks] = *reinterpret_cast<const bf16x8*>(
                &s_mem[(wbase + mt * 16 + c) * HS + ks * 32 + quad * 8]);

    const uint4* w1q = reinterpret_cast<const uint4*>(w1p);
#pragma unroll
    for (int nt = 0; nt < 8; nt++) {
        f32x4 acc[4] = {zf, zf, zf, zf};
#pragma unroll
        for (int ks = 0; ks < 4; ks++) {
            union { uint4 q; bf16x8 s; } bb;
            bb.q = w1q[(nt * 4 + ks) * 64 + lane];
#pragma unroll
            for (int mt = 0; mt < 4; mt++)
                acc[mt] = __builtin_amdgcn_mfma_f32_16x16x32_bf16(a2[mt][ks], bb.s, acc[mt], 0, 0, 0);
        }
        float bias = b1[nt * 16 + c];
#pragma unroll
        for (int mt = 0; mt < 4; mt++)
#pragma unroll
            for (int r = 0; r < 4; r++) {
                float h = fmaxf(acc[mt][r] + bias, 0.0f);
                s_mem[(wbase + mt * 16 + quad * 4 + r) * HS + nt * 16 + c] = f2bf(h);
            }
    }

    // ---- layer 3: h2@w2 (N padded to 16, cols 0..2 valid) ----
    bf16x8 a3[4][4];
#pragma unroll
    for (int mt = 0; mt < 4; mt++)
#pragma unroll
        for (int ks = 0; ks < 4; ks++)
            a3[mt][ks] = *reinterpret_cast<const bf16x8*>(
                &s_mem[(wbase + mt * 16 + c) * HS + ks * 32 + quad * 8]);

    const uint4* w2q = reinterpret_cast<const uint4*>(w2p);
    f32x4 acc3[4] = {zf, zf, zf, zf};
#pragma unroll
    for (int ks = 0; ks < 4; ks++) {
        union { uint4 q; bf16x8 s; } bb;
        bb.q = w2q[ks * 64 + lane];
#pragma unroll
        for (int mt = 0; mt < 4; mt++)
            acc3[mt] = __builtin_amdgcn_mfma_f32_16x16x32_bf16(a3[mt][ks], bb.s, acc3[mt], 0, 0, 0);
    }

    // ---- epilogue: sigmoid, weight by alpha*T_excl, reduce ----
    float b2c = (c < 3) ? b2[c] : 0.0f;
    float csum = 0.0f;
#pragma unroll
    for (int mt = 0; mt < 4; mt++)
#pragma unroll
        for (int r = 0; r < 4; r++) {
            int m = wbase + mt * 16 + quad * 4 + r;
            float pre = acc3[mt][r] + b2c;
            float sg = 1.0f / (1.0f + expf(-pre));
            float Texcl = (m == 0) ? 1.0f : s_P[m - 1];
            float wgt = s_alpha[m] * Texcl;
            csum += wgt * sg;
        }
    csum += __shfl_xor(csum, 16);
    csum += __shfl_xor(csum, 32);
    if (quad == 0 && c < 3) atomicAdd(&s_out[c], csum);
    __syncthreads();
    if (t < 3) out[n * 3 + t] = s_out[t] + s_P[SAMP - 1];
}

// ---------- fallback (scalar MLP, fp32 grids) if ws too small ----------
__global__ __launch_bounds__(256, 2) void dvgo_fallback(
        const float* __restrict__ pts, const float* __restrict__ viewdirs,
        const float* __restrict__ dgrid, const float* __restrict__ kgrid,
        const float* __restrict__ w0, const float* __restrict__ b0,
        const float* __restrict__ w1, const float* __restrict__ b1,
        const float* __restrict__ w2, const float* __restrict__ b2,
        float* __restrict__ out)
{
    const int n = blockIdx.x;
    const int t = threadIdx.x;
    __shared__ float  s_alpha[SAMP];
    __shared__ float  s_P[SAMP];
    __shared__ float  s_h1[SAMP * 33];  // packed later per chunk
    __shared__ float  s_red[12];

    const float* p = pts + ((size_t)n * SAMP + t) * 3;
    float pc[3] = {p[0], p[1], p[2]};
    int i0[3]; float fr[3];
#pragma unroll
    for (int d = 0; d < 3; d++) {
        float uu = (pc[d] + 1.0f) * 0.5f * (float)(G - 1);
        uu = fminf(fmaxf(uu, 0.0f), (float)(G - 1));
        int i = (int)floorf(uu);
        if (i > G - 2) i = G - 2;
        i0[d] = i; fr[d] = uu - (float)i;
    }
    float dens = 0.0f, k0v[CK0];
#pragma unroll
    for (int ch = 0; ch < CK0; ch++) k0v[ch] = 0.0f;
#pragma unroll
    for (int cx = 0; cx < 2; cx++)
#pragma unroll
        for (int cy = 0; cy < 2; cy++)
#pragma unroll
            for (int cz = 0; cz < 2; cz++) {
                float w = (cx ? fr[0] : 1.0f - fr[0]) * (cy ? fr[1] : 1.0f - fr[1]) * (cz ? fr[2] : 1.0f - fr[2]);
                int vidx = ((i0[0] + cx) * G + (i0[1] + cy)) * G + (i0[2] + cz);
                dens += w * dgrid[vidx];
#pragma unroll
                for (int ch = 0; ch < CK0; ch++) k0v[ch] += w * kgrid[(size_t)ch * G3 + vidx];
            }
    float xs = dens + ACT_SHIFT;
    float sp = (xs > 20.0f) ? xs : log1pf(expf(xs));
    float alpha = 1.0f - expf(-sp * 0.5f);
    s_alpha[t] = alpha; s_P[t] = 1.0f - alpha;
    __syncthreads();
#pragma unroll
    for (int off = 1; off < SAMP; off <<= 1) {
        float v = (t >= off) ? s_P[t - off] : 1.0f;
        __syncthreads();
        s_P[t] *= v;
        __syncthreads();
    }
    float v0 = viewdirs[n * 3 + 0], v1 = viewdirs[n * 3 + 1], v2 = viewdirs[n * 3 + 2];
    float inv = 1.0f / sqrtf(v0 * v0 + v1 * v1 + v2 * v2);
    v0 *= inv; v1 *= inv; v2 *= inv;
    float feat[39];
#pragma unroll
    for (int ch = 0; ch < CK0; ch++) feat[ch] = k0v[ch];
    feat[12] = v0; feat[13] = v1; feat[14] = v2;
    float vd3[3] = {v0, v1, v2};
#pragma unroll
    for (int i = 0; i < 3; i++)
#pragma unroll
        for (int j = 0; j < 4; j++) {
            float a = vd3[i] * (float)(1 << j);
            feat[15 + i * 4 + j] = sinf(a);
            feat[27 + i * 4 + j] = cosf(a);
        }
    float h1[HID];
#pragma unroll 1
    for (int ch = 0; ch < 4; ch++) {
        float acc[32];
#pragma unroll
        for (int j = 0; j < 32; j++) acc[j] = b0[ch * 32 + j];
#pragma unroll
        for (int k = 0; k < 39; k++) {
            float f = feat[k];
#pragma unroll
            for (int j = 0; j < 32; j++) acc[j] = fmaf(f, w0[k * HID + ch * 32 + j], acc[j]);
        }
#pragma unroll
        for (int j = 0; j < 32; j++) h1[ch * 32 + j] = fmaxf(acc[j], 0.0f);
    }
    float rgbpre[3] = {b2[0], b2[1], b2[2]};
#pragma unroll 1
    for (int ch = 0; ch < 4; ch++) {
        float acc[32];
#pragma unroll
        for (int j = 0; j < 32; j++) acc[j] = b1[ch * 32 + j];
#pragma unroll 4
        for (int k = 0; k < HID; k++) {
            float hk = h1[k];
#pragma unroll
            for (int j = 0; j < 32; j++) acc[j] = fmaf(hk, w1[k * HID + ch * 32 + j], acc[j]);
        }
#pragma unroll
        for (int j = 0; j < 32; j++) {
            float h2 = fmaxf(acc[j], 0.0f);
            int jj = ch * 32 + j;
            rgbpre[0] = fmaf(h2, w2[jj * 3 + 0], rgbpre[0]);
            rgbpre[1] = fmaf(h2, w2[jj * 3 + 1], rgbpre[1]);
            rgbpre[2] = fmaf(h2, w2[jj * 3 + 2], rgbpre[2]);
        }
    }
    float T_excl = (t == 0) ? 1.0f : s_P[t - 1];
    float wgt = s_alpha[t] * T_excl;
    float c0 = wgt / (1.0f + expf(-rgbpre[0]));
    float c1 = wgt / (1.0f + expf(-rgbpre[1]));
    float c2 = wgt / (1.0f + expf(-rgbpre[2]));
#pragma unroll
    for (int off = 32; off > 0; off >>= 1) {
        c0 += __shfl_down(c0, off);
        c1 += __shfl_down(c1, off);
        c2 += __shfl_down(c2, off);
    }
    if ((t & 63) == 0) {
        int wv = t >> 6;
        s_red[wv * 3 + 0] = c0; s_red[wv * 3 + 1] = c1; s_red[wv * 3 + 2] = c2;
    }
    __syncthreads();
    if (t == 0) {
        float alast = s_P[SAMP - 1];
        float o0 = alast, o1 = alast, o2 = alast;
#pragma unroll
        for (int wv = 0; wv < 4; wv++) {
            o0 += s_red[wv * 3 + 0]; o1 += s_red[wv * 3 + 1]; o2 += s_red[wv * 3 + 2];
        }
        out[n * 3 + 0] = o0; out[n * 3 + 1] = o1; out[n * 3 + 2] = o2;
    }
    (void)s_h1;
}

extern "C" void kernel_launch(void* const* d_in, const int* in_sizes, int n_in,
                              void* d_out, int out_size, void* d_ws, size_t ws_size,
                              hipStream_t stream) {
    const float* pts      = (const float*)d_in[0];
    const float* viewdirs = (const float*)d_in[1];
    const float* dgrid    = (const float*)d_in[2];
    const float* kgrid    = (const float*)d_in[3];
    const float* w0       = (const float*)d_in[4];
    const float* b0       = (const float*)d_in[5];
    const float* w1       = (const float*)d_in[6];
    const float* b1       = (const float*)d_in[7];
    const float* w2       = (const float*)d_in[8];
    const float* b2       = (const float*)d_in[9];
    float* out = (float*)d_out;

    const size_t VOXB = (size_t)G3 * 32;          // 131,072,000
    const size_t W0PE = 16 * 512, W1PE = 32 * 512, W2PE = 4 * 512;  // elements
    const size_t TOTB = VOXB + (W0PE + W1PE + W2PE) * 2;

    if (ws_size >= TOTB) {
        unsigned short* vox  = (unsigned short*)d_ws;
        unsigned short* w0pp = (unsigned short*)((char*)d_ws + VOXB);
        unsigned short* w1pp = w0pp + W0PE;
        unsigned short* w2pp = w1pp + W1PE;
        prepass_kernel<<<G3 / 4 / 256, 256, 0, stream>>>(dgrid, kgrid, vox);
        pack_weights<<<1, 256, 0, stream>>>(w0, w1, w2, w0pp, w1pp, w2pp);
        dvgo_mfma<<<NRAYS, 256, 0, stream>>>(pts, viewdirs, vox, w0pp, w1pp, w2pp,
                                             b0, b1, b2, out);
    } else {
        dvgo_fallback<<<NRAYS, SAMP, 0, stream>>>(pts, viewdirs, dgrid, kgrid,
                                                  w0, b0, w1, b1, w2, b2, out);
    }
}

// Round 4
// 519.710 us; speedup vs baseline: 3.2794x; 1.0612x over previous
//
#include <hip/hip_runtime.h>
#include <hip/hip_fp16.h>

#define G      160
#define G3     (G*G*G)
#define NRAYS  4096
#define SAMP   256
#define CK0    12
#define HID    128

// log(1/(1-0.01) - 1) = -log(99)
#define ACT_SHIFT (-4.59511985013459f)

#define FS 72     // feat slab row stride (halves); 144 B = 9*16 -> b128-aligned
#define HS 136    // h slab row stride (halves);   272 B = 17*16 -> b128-aligned
#define SLABH (64 * HS)   // per-wave slab (halves); feat (64*FS) overlays low part

typedef __attribute__((ext_vector_type(8))) _Float16 f16x8;
typedef __attribute__((ext_vector_type(4))) float    f32x4;

__device__ __forceinline__ unsigned pkrtz_u(float a, float b) {
    typedef __attribute__((ext_vector_type(2))) __fp16 fp16v2;
    union { fp16v2 h; unsigned u; } cv;
    cv.h = __builtin_amdgcn_cvt_pkrtz(a, b);
    return cv.u;
}

// ---------- prepass: interleave k0 + density into [x][y][z][16] fp16 ----------
// voxel layout (halves): 0..11 = k0 ch0..11, 12..14 = 0, 15 = density
__global__ __launch_bounds__(256) void prepass_kernel(
        const float* __restrict__ dgrid,
        const float* __restrict__ kgrid,
        unsigned short* __restrict__ vox)
{
    int v4 = (blockIdx.x * 256 + threadIdx.x) * 4;
    if (v4 >= G3) return;
    union F4 { float4 v; float f[4]; };
    F4 d; d.v = *reinterpret_cast<const float4*>(dgrid + v4);
    F4 kk[CK0];
#pragma unroll
    for (int c = 0; c < CK0; c++)
        kk[c].v = *reinterpret_cast<const float4*>(kgrid + (size_t)c * G3 + v4);
#pragma unroll
    for (int i = 0; i < 4; i++) {
        uint4 qa, qb;
        qa.x = pkrtz_u(kk[0].f[i],  kk[1].f[i]);
        qa.y = pkrtz_u(kk[2].f[i],  kk[3].f[i]);
        qa.z = pkrtz_u(kk[4].f[i],  kk[5].f[i]);
        qa.w = pkrtz_u(kk[6].f[i],  kk[7].f[i]);
        qb.x = pkrtz_u(kk[8].f[i],  kk[9].f[i]);
        qb.y = pkrtz_u(kk[10].f[i], kk[11].f[i]);
        qb.z = 0u;
        qb.w = pkrtz_u(0.0f, d.f[i]);
        uint4* dst = reinterpret_cast<uint4*>(vox + (size_t)(v4 + i) * 16);
        dst[0] = qa;
        dst[1] = qb;
    }
}

// ---------- weight prepack (parallel, fp16), B-frag order for mfma 16x16x32 ----------
// k = ks*32 + (l>>4)*8 + j, n = nt*16 + (l&15); element stored at [(f*64+l)*8+j]
#define W0PE (16 * 512)
#define W1PE (32 * 512)
#define W2PE (4 * 512)
__global__ __launch_bounds__(256) void pack_weights(
        const float* __restrict__ w0, const float* __restrict__ w1,
        const float* __restrict__ w2,
        unsigned short* __restrict__ w0p, unsigned short* __restrict__ w1p,
        unsigned short* __restrict__ w2p)
{
    int idx = blockIdx.x * 256 + threadIdx.x;
    if (idx < W0PE) {
        int f = idx >> 9, r = idx & 511, l = r >> 3, j = r & 7;
        int nt = f >> 1, ks = f & 1;
        int k = ks * 32 + ((l >> 4) << 3) + j;
        int nn = nt * 16 + (l & 15);
        w0p[idx] = (k < 39) ? __half_as_ushort(__float2half(w0[k * HID + nn]))
                            : (unsigned short)0;
    } else if (idx < W0PE + W1PE) {
        int m = idx - W0PE;
        int f = m >> 9, r = m & 511, l = r >> 3, j = r & 7;
        int nt = f >> 2, ks = f & 3;
        int k = ks * 32 + ((l >> 4) << 3) + j;
        int nn = nt * 16 + (l & 15);
        w1p[m] = __half_as_ushort(__float2half(w1[k * HID + nn]));
    } else if (idx < W0PE + W1PE + W2PE) {
        int m = idx - W0PE - W1PE;
        int ks = m >> 9, r = m & 511, l = r >> 3, j = r & 7;
        int k = ks * 32 + ((l >> 4) << 3) + j;
        int nn = l & 15;
        w2p[m] = (nn < 3) ? __half_as_ushort(__float2half(w2[k * 3 + nn]))
                          : (unsigned short)0;
    }
}

// ---------- main: one block per ray; 4 waves; per-wave private LDS slab ----------
__global__ __launch_bounds__(256) void dvgo_mfma(
        const float* __restrict__ pts,
        const float* __restrict__ viewdirs,
        const unsigned short* __restrict__ vox,
        const unsigned short* __restrict__ w0p,
        const unsigned short* __restrict__ w1p,
        const unsigned short* __restrict__ w2p,
        const float* __restrict__ b0, const float* __restrict__ b1,
        const float* __restrict__ b2,
        float* __restrict__ out)
{
    __shared__ __half s_mem[4 * SLABH];   // 69632 B
    __shared__ float  s_wgt[SAMP];
    __shared__ float  s_wave[4];
    __shared__ unsigned s_u[16];          // slots 2..15 = feat cols 12..39 (fp16 pairs)
    __shared__ float  s_out[4];

    const int n    = blockIdx.x;
    const int t    = threadIdx.x;
    const int lane = t & 63;
    const int wv   = t >> 6;
    const int wbase = wv << 6;
    const int c    = lane & 15;
    const int quad = lane >> 4;
    __half* slab = s_mem + wv * SLABH;
    const int lr = lane;                  // local row within slab

    if (t < 4) s_out[t] = 0.0f;

    // ---- view embedding: computed once per block (cols 12..39 are ray-uniform) ----
    if (t < 14) {
        float v0 = viewdirs[n * 3 + 0];
        float v1 = viewdirs[n * 3 + 1];
        float v2 = viewdirs[n * 3 + 2];
        float inv = rsqrtf(v0 * v0 + v1 * v1 + v2 * v2);
        float vd[3] = {v0 * inv, v1 * inv, v2 * inv};
        float fv[2];
#pragma unroll
        for (int e = 0; e < 2; e++) {
            int col = 12 + 2 * t + e;
            float f;
            if (col < 15)      f = vd[col - 12];
            else if (col < 27) { int s = col - 15; f = __sinf(vd[s >> 2] * (float)(1 << (s & 3))); }
            else if (col < 39) { int s = col - 27; f = __cosf(vd[s >> 2] * (float)(1 << (s & 3))); }
            else               f = 0.0f;
            fv[e] = f;
        }
        s_u[t + 2] = pkrtz_u(fv[0], fv[1]);
    }

    // ---- trilinear gather (fp16 packed lerp; density in fp32) ----
    const float* p = pts + ((size_t)n * SAMP + t) * 3;
    float pc[3] = {p[0], p[1], p[2]};
    int   i0[3];
    float fr[3];
#pragma unroll
    for (int d = 0; d < 3; d++) {
        float uu = (pc[d] + 1.0f) * 0.5f * (float)(G - 1);
        uu = fminf(fmaxf(uu, 0.0f), (float)(G - 1));
        int i = (int)floorf(uu);
        if (i > G - 2) i = G - 2;
        i0[d] = i;
        fr[d] = uu - (float)i;
    }

    __half2 accA0 = __float2half2_rn(0.0f), accA1 = accA0, accA2 = accA0, accA3 = accA0;
    __half2 accB0 = accA0, accB1 = accA0;
    float dens = 0.0f;

#pragma unroll
    for (int cx = 0; cx < 2; cx++) {
        float wx = cx ? fr[0] : 1.0f - fr[0];
#pragma unroll
        for (int cy = 0; cy < 2; cy++) {
            float wxy = wx * (cy ? fr[1] : 1.0f - fr[1]);
#pragma unroll
            for (int cz = 0; cz < 2; cz++) {
                float w = wxy * (cz ? fr[2] : 1.0f - fr[2]);
                int vidx = ((i0[0] + cx) * G + (i0[1] + cy)) * G + (i0[2] + cz);
                const uint4* q = reinterpret_cast<const uint4*>(vox) + (size_t)vidx * 2;
                union { uint4 q; __half2 h2[4]; } A, B;
                A.q = q[0];
                B.q = q[1];
                __half2 wh = __half2half2(__float2half(w));
                accA0 = __hfma2(wh, A.h2[0], accA0);
                accA1 = __hfma2(wh, A.h2[1], accA1);
                accA2 = __hfma2(wh, A.h2[2], accA2);
                accA3 = __hfma2(wh, A.h2[3], accA3);
                accB0 = __hfma2(wh, B.h2[0], accB0);
                accB1 = __hfma2(wh, B.h2[1], accB1);
                dens += w * __half2float(__high2half(B.h2[3]));
            }
        }
    }

    // ---- alpha + wave-level cumprod scan (no LDS ping-pong) ----
    float xs = dens + ACT_SHIFT;
    float sp = fmaxf(xs, 0.0f) + __logf(1.0f + __expf(-fabsf(xs)));
    float alpha = 1.0f - __expf(-sp * 0.5f);

    float xi = 1.0f - alpha;
#pragma unroll
    for (int off = 1; off < 64; off <<= 1) {
        float y = __shfl_up(xi, off);
        if (lane >= off) xi *= y;
    }
    if (lane == 63) s_wave[wv] = xi;

    __syncthreads();   // barrier A: s_u + s_wave visible

    // ---- exclusive transmittance -> per-sample weight (wave-local store) ----
    float prefix = 1.0f;
#pragma unroll
    for (int u = 0; u < 3; u++)
        if (u < wv) prefix *= s_wave[u];
    float xp = __shfl_up(xi, 1);
    float Texcl = prefix * ((lane == 0) ? 1.0f : xp);
    s_wgt[t] = alpha * Texcl;

    // ---- feat row -> slab (chunks 0..1 ARE the gather accumulators) ----
    {
        uint4 q0, q1;
        union { __half2 h; unsigned u; } cv;
        cv.h = accA0; q0.x = cv.u;
        cv.h = accA1; q0.y = cv.u;
        cv.h = accA2; q0.z = cv.u;
        cv.h = accA3; q0.w = cv.u;
        cv.h = accB0; q1.x = cv.u;
        cv.h = accB1; q1.y = cv.u;
        q1.z = s_u[2];
        q1.w = s_u[3];
        *reinterpret_cast<uint4*>(slab + lr * FS)     = q0;  // cols 0..7
        *reinterpret_cast<uint4*>(slab + lr * FS + 8) = q1;  // cols 8..15
        const uint4* uq = reinterpret_cast<const uint4*>(s_u);
        *reinterpret_cast<uint4*>(slab + lr * FS + 16) = uq[1];  // cols 16..23
        *reinterpret_cast<uint4*>(slab + lr * FS + 24) = uq[2];  // cols 24..31
        *reinterpret_cast<uint4*>(slab + lr * FS + 32) = uq[3];  // cols 32..39
        // cols 40..63 left garbage: never loaded (ks=1 frags zeroed for quad>0)
    }

    const f32x4 zf = {0.0f, 0.0f, 0.0f, 0.0f};
    const f16x8 zfrag = {};

    // ---- A1 fragments from feat (wave-private; DS pipe is in-order, no barrier) ----
    f16x8 a1[4][2];
#pragma unroll
    for (int mt = 0; mt < 4; mt++) {
        a1[mt][0] = *reinterpret_cast<const f16x8*>(slab + (mt * 16 + c) * FS + quad * 8);
        a1[mt][1] = zfrag;
        if (quad == 0)
            a1[mt][1] = *reinterpret_cast<const f16x8*>(slab + (mt * 16 + c) * FS + 32);
    }

    // ---- layer 1: feat @ w0 + b0, relu -> h1 (slab, stride HS) ----
    const uint4* w0q = reinterpret_cast<const uint4*>(w0p);
#pragma unroll
    for (int nt = 0; nt < 8; nt++) {
        union { uint4 q; f16x8 s; } bA, bB;
        bA.q = w0q[(nt * 2 + 0) * 64 + lane];
        bB.q = w0q[(nt * 2 + 1) * 64 + lane];
        f32x4 acc[4];
#pragma unroll
        for (int mt = 0; mt < 4; mt++) {
            f32x4 tmp = __builtin_amdgcn_mfma_f32_16x16x32_f16(a1[mt][0], bA.s, zf, 0, 0, 0);
            acc[mt]   = __builtin_amdgcn_mfma_f32_16x16x32_f16(a1[mt][1], bB.s, tmp, 0, 0, 0);
        }
        float bias = b0[nt * 16 + c];
#pragma unroll
        for (int mt = 0; mt < 4; mt++)
#pragma unroll
            for (int r = 0; r < 4; r++)
                slab[(mt * 16 + quad * 4 + r) * HS + nt * 16 + c] =
                    __float2half(fmaxf(acc[mt][r] + bias, 0.0f));
    }

    // ---- layer 2: h1 @ w1 + b1, relu -> h2 (same slab rows) ----
    f16x8 a2[4][4];
#pragma unroll
    for (int mt = 0; mt < 4; mt++)
#pragma unroll
        for (int ks = 0; ks < 4; ks++)
            a2[mt][ks] = *reinterpret_cast<const f16x8*>(
                slab + (mt * 16 + c) * HS + ks * 32 + quad * 8);

    const uint4* w1q = reinterpret_cast<const uint4*>(w1p);
#pragma unroll
    for (int nt = 0; nt < 8; nt++) {
        f32x4 acc[4] = {zf, zf, zf, zf};
#pragma unroll
        for (int ks = 0; ks < 4; ks++) {
            union { uint4 q; f16x8 s; } bb;
            bb.q = w1q[(nt * 4 + ks) * 64 + lane];
#pragma unroll
            for (int mt = 0; mt < 4; mt++)
                acc[mt] = __builtin_amdgcn_mfma_f32_16x16x32_f16(a2[mt][ks], bb.s, acc[mt], 0, 0, 0);
        }
        float bias = b1[nt * 16 + c];
#pragma unroll
        for (int mt = 0; mt < 4; mt++)
#pragma unroll
            for (int r = 0; r < 4; r++)
                slab[(mt * 16 + quad * 4 + r) * HS + nt * 16 + c] =
                    __float2half(fmaxf(acc[mt][r] + bias, 0.0f));
    }

    // ---- layer 3: h2 @ w2 (N padded to 16; cols 0..2 valid) ----
    f16x8 a3[4][4];
#pragma unroll
    for (int mt = 0; mt < 4; mt++)
#pragma unroll
        for (int ks = 0; ks < 4; ks++)
            a3[mt][ks] = *reinterpret_cast<const f16x8*>(
                slab + (mt * 16 + c) * HS + ks * 32 + quad * 8);

    const uint4* w2q = reinterpret_cast<const uint4*>(w2p);
    f32x4 acc3[4] = {zf, zf, zf, zf};
#pragma unroll
    for (int ks = 0; ks < 4; ks++) {
        union { uint4 q; f16x8 s; } bb;
        bb.q = w2q[ks * 64 + lane];
#pragma unroll
        for (int mt = 0; mt < 4; mt++)
            acc3[mt] = __builtin_amdgcn_mfma_f32_16x16x32_f16(a3[mt][ks], bb.s, acc3[mt], 0, 0, 0);
    }

    // ---- epilogue: sigmoid, weight, reduce ----
    float b2c = (c < 3) ? b2[c] : 0.0f;
    float csum = 0.0f;
#pragma unroll
    for (int mt = 0; mt < 4; mt++)
#pragma unroll
        for (int r = 0; r < 4; r++) {
            int m = wbase + mt * 16 + quad * 4 + r;
            float pre = acc3[mt][r] + b2c;
            float sg = 1.0f / (1.0f + __expf(-pre));
            csum += s_wgt[m] * sg;
        }
    csum += __shfl_xor(csum, 16);
    csum += __shfl_xor(csum, 32);
    if (quad == 0 && c < 3) atomicAdd(&s_out[c], csum);

    __syncthreads();   // barrier B
    if (t < 3) {
        float alast = s_wave[0] * s_wave[1] * s_wave[2] * s_wave[3];
        out[n * 3 + t] = s_out[t] + alast;
    }
}

// ---------- fallback (scalar fp32) if ws too small ----------
__global__ __launch_bounds__(256, 2) void dvgo_fallback(
        const float* __restrict__ pts, const float* __restrict__ viewdirs,
        const float* __restrict__ dgrid, const float* __restrict__ kgrid,
        const float* __restrict__ w0, const float* __restrict__ b0,
        const float* __restrict__ w1, const float* __restrict__ b1,
        const float* __restrict__ w2, const float* __restrict__ b2,
        float* __restrict__ out)
{
    const int n = blockIdx.x;
    const int t = threadIdx.x;
    __shared__ float s_alpha[SAMP];
    __shared__ float s_P[SAMP];
    __shared__ float s_red[12];

    const float* p = pts + ((size_t)n * SAMP + t) * 3;
    float pc[3] = {p[0], p[1], p[2]};
    int i0[3]; float fr[3];
#pragma unroll
    for (int d = 0; d < 3; d++) {
        float uu = (pc[d] + 1.0f) * 0.5f * (float)(G - 1);
        uu = fminf(fmaxf(uu, 0.0f), (float)(G - 1));
        int i = (int)floorf(uu);
        if (i > G - 2) i = G - 2;
        i0[d] = i; fr[d] = uu - (float)i;
    }
    float dens = 0.0f, k0v[CK0];
#pragma unroll
    for (int ch = 0; ch < CK0; ch++) k0v[ch] = 0.0f;
#pragma unroll
    for (int cx = 0; cx < 2; cx++)
#pragma unroll
        for (int cy = 0; cy < 2; cy++)
#pragma unroll
            for (int cz = 0; cz < 2; cz++) {
                float w = (cx ? fr[0] : 1.0f - fr[0]) * (cy ? fr[1] : 1.0f - fr[1]) * (cz ? fr[2] : 1.0f - fr[2]);
                int vidx = ((i0[0] + cx) * G + (i0[1] + cy)) * G + (i0[2] + cz);
                dens += w * dgrid[vidx];
#pragma unroll
                for (int ch = 0; ch < CK0; ch++) k0v[ch] += w * kgrid[(size_t)ch * G3 + vidx];
            }
    float xs = dens + ACT_SHIFT;
    float sp = (xs > 20.0f) ? xs : log1pf(expf(xs));
    float alpha = 1.0f - expf(-sp * 0.5f);
    s_alpha[t] = alpha; s_P[t] = 1.0f - alpha;
    __syncthreads();
#pragma unroll
    for (int off = 1; off < SAMP; off <<= 1) {
        float v = (t >= off) ? s_P[t - off] : 1.0f;
        __syncthreads();
        s_P[t] *= v;
        __syncthreads();
    }
    float v0 = viewdirs[n * 3 + 0], v1 = viewdirs[n * 3 + 1], v2 = viewdirs[n * 3 + 2];
    float inv = 1.0f / sqrtf(v0 * v0 + v1 * v1 + v2 * v2);
    v0 *= inv; v1 *= inv; v2 *= inv;
    float feat[39];
#pragma unroll
    for (int ch = 0; ch < CK0; ch++) feat[ch] = k0v[ch];
    feat[12] = v0; feat[13] = v1; feat[14] = v2;
    float vd3[3] = {v0, v1, v2};
#pragma unroll
    for (int i = 0; i < 3; i++)
#pragma unroll
        for (int j = 0; j < 4; j++) {
            float a = vd3[i] * (float)(1 << j);
            feat[15 + i * 4 + j] = sinf(a);
            feat[27 + i * 4 + j] = cosf(a);
        }
    float h1[HID];
#pragma unroll 1
    for (int ch = 0; ch < 4; ch++) {
        float acc[32];
#pragma unroll
        for (int j = 0; j < 32; j++) acc[j] = b0[ch * 32 + j];
#pragma unroll
        for (int k = 0; k < 39; k++) {
            float f = feat[k];
#pragma unroll
            for (int j = 0; j < 32; j++) acc[j] = fmaf(f, w0[k * HID + ch * 32 + j], acc[j]);
        }
#pragma unroll
        for (int j = 0; j < 32; j++) h1[ch * 32 + j] = fmaxf(acc[j], 0.0f);
    }
    float rgbpre[3] = {b2[0], b2[1], b2[2]};
#pragma unroll 1
    for (int ch = 0; ch < 4; ch++) {
        float acc[32];
#pragma unroll
        for (int j = 0; j < 32; j++) acc[j] = b1[ch * 32 + j];
#pragma unroll 4
        for (int k = 0; k < HID; k++) {
            float hk = h1[k];
#pragma unroll
            for (int j = 0; j < 32; j++) acc[j] = fmaf(hk, w1[k * HID + ch * 32 + j], acc[j]);
        }
#pragma unroll
        for (int j = 0; j < 32; j++) {
            float h2 = fmaxf(acc[j], 0.0f);
            int jj = ch * 32 + j;
            rgbpre[0] = fmaf(h2, w2[jj * 3 + 0], rgbpre[0]);
            rgbpre[1] = fmaf(h2, w2[jj * 3 + 1], rgbpre[1]);
            rgbpre[2] = fmaf(h2, w2[jj * 3 + 2], rgbpre[2]);
        }
    }
    float T_excl = (t == 0) ? 1.0f : s_P[t - 1];
    float wgt = s_alpha[t] * T_excl;
    float c0 = wgt / (1.0f + expf(-rgbpre[0]));
    float c1 = wgt / (1.0f + expf(-rgbpre[1]));
    float c2 = wgt / (1.0f + expf(-rgbpre[2]));
#pragma unroll
    for (int off = 32; off > 0; off >>= 1) {
        c0 += __shfl_down(c0, off);
        c1 += __shfl_down(c1, off);
        c2 += __shfl_down(c2, off);
    }
    if ((t & 63) == 0) {
        int wvv = t >> 6;
        s_red[wvv * 3 + 0] = c0; s_red[wvv * 3 + 1] = c1; s_red[wvv * 3 + 2] = c2;
    }
    __syncthreads();
    if (t == 0) {
        float alast = s_P[SAMP - 1];
        float o0 = alast, o1 = alast, o2 = alast;
#pragma unroll
        for (int wvv = 0; wvv < 4; wvv++) {
            o0 += s_red[wvv * 3 + 0]; o1 += s_red[wvv * 3 + 1]; o2 += s_red[wvv * 3 + 2];
        }
        out[n * 3 + 0] = o0; out[n * 3 + 1] = o1; out[n * 3 + 2] = o2;
    }
}

extern "C" void kernel_launch(void* const* d_in, const int* in_sizes, int n_in,
                              void* d_out, int out_size, void* d_ws, size_t ws_size,
                              hipStream_t stream) {
    const float* pts      = (const float*)d_in[0];
    const float* viewdirs = (const float*)d_in[1];
    const float* dgrid    = (const float*)d_in[2];
    const float* kgrid    = (const float*)d_in[3];
    const float* w0       = (const float*)d_in[4];
    const float* b0       = (const float*)d_in[5];
    const float* w1       = (const float*)d_in[6];
    const float* b1       = (const float*)d_in[7];
    const float* w2       = (const float*)d_in[8];
    const float* b2       = (const float*)d_in[9];
    float* out = (float*)d_out;

    const size_t VOXB = (size_t)G3 * 32;
    const size_t TOTB = VOXB + (size_t)(W0PE + W1PE + W2PE) * 2;

    if (ws_size >= TOTB) {
        unsigned short* vox  = (unsigned short*)d_ws;
        unsigned short* w0pp = (unsigned short*)((char*)d_ws + VOXB);
        unsigned short* w1pp = w0pp + W0PE;
        unsigned short* w2pp = w1pp + W1PE;
        prepass_kernel<<<G3 / 4 / 256, 256, 0, stream>>>(dgrid, kgrid, vox);
        pack_weights<<<(W0PE + W1PE + W2PE + 255) / 256, 256, 0, stream>>>(
            w0, w1, w2, w0pp, w1pp, w2pp);
        dvgo_mfma<<<NRAYS, 256, 0, stream>>>(pts, viewdirs, vox, w0pp, w1pp, w2pp,
                                             b0, b1, b2, out);
    } else {
        dvgo_fallback<<<NRAYS, SAMP, 0, stream>>>(pts, viewdirs, dgrid, kgrid,
                                                  w0, b0, w1, b1, w2, b2, out);
    }
}